// Round 1
// baseline (454.952 us; speedup 1.0000x reference)
//
#include <hip/hip_runtime.h>
#include <hip/hip_bf16.h>
#include <stdint.h>

typedef __attribute__((ext_vector_type(8))) short short8;
typedef __attribute__((ext_vector_type(4))) float f32x4;
typedef __attribute__((ext_vector_type(4))) unsigned short ushort4_t;

#define SEG 16

__device__ __forceinline__ float bf2f(unsigned short u) {
  unsigned int x = ((unsigned int)u) << 16;
  return __uint_as_float(x);
}
__device__ __forceinline__ unsigned short f2bf(float f) {
  unsigned int u = __float_as_uint(f);
  u += 0x7fffu + ((u >> 16) & 1u);
  return (unsigned short)(u >> 16);
}

// ---------------- cast fp32 -> bf16 (vectorized) ----------------
__global__ void cast_f32_bf16(const float* __restrict__ in,
                              unsigned short* __restrict__ out, int n4) {
  const int stride = gridDim.x * blockDim.x;
  for (int i = blockIdx.x * blockDim.x + threadIdx.x; i < n4; i += stride) {
    const float4 v = ((const float4*)in)[i];
    ushort4_t o;
    o[0] = f2bf(v.x); o[1] = f2bf(v.y); o[2] = f2bf(v.z); o[3] = f2bf(v.w);
    ((ushort4_t*)out)[i] = o;
  }
}

// ---------------- GEMM: C[M,N] = A[M,K] * B[N,K]^T ----------------
// A row-major [M,K] bf16, B row-major [N,K] bf16 (i.e. B^T layout), C OutT.
// fm_cols: apply elu(x)+1 to output columns < fm_cols (in fp32, pre-store).
// 128x128 tile, BK=32, 256 threads = 4 waves in 2x2, 16x16x32 bf16 MFMA.
template <typename OutT>
__global__ __launch_bounds__(256) void gemm_bt(
    const unsigned short* __restrict__ A, const unsigned short* __restrict__ Bm,
    OutT* __restrict__ C, int M, int N, int K, int ldc, int fm_cols) {
  __shared__ unsigned short As[128][40];  // +8 bf16 pad (16B) keeps alignment, kills po2 bank stride
  __shared__ unsigned short Bs[128][40];
  const int tid = threadIdx.x;
  const int lane = tid & 63;
  const int wave = tid >> 6;
  const int wr = wave >> 1, wc = wave & 1;  // 2x2 wave grid, each 64x64 out
  const size_t arow0 = (size_t)blockIdx.y * 128;
  const size_t bcol0 = (size_t)blockIdx.x * 128;
  f32x4 acc[4][4] = {};
  const int sr = tid >> 2;         // staging row 0..63 (+64)
  const int sv = (tid & 3) * 8;    // staging elem offset in row: 0,8,16,24
  const int fr = lane & 15;        // fragment row/col
  const int ko = (lane >> 4) * 8;  // fragment K-octet

  for (int k0 = 0; k0 < K; k0 += 32) {
    __syncthreads();
#pragma unroll
    for (int i = 0; i < 2; ++i) {
      const int row = sr + i * 64;
      *(short8*)&As[row][sv] = *(const short8*)(A + (arow0 + row) * K + k0 + sv);
      *(short8*)&Bs[row][sv] = *(const short8*)(Bm + (bcol0 + row) * K + k0 + sv);
    }
    __syncthreads();
    short8 af[4], bfr[4];
#pragma unroll
    for (int m = 0; m < 4; ++m)
      af[m] = *(const short8*)&As[wr * 64 + m * 16 + fr][ko];
#pragma unroll
    for (int n = 0; n < 4; ++n)
      bfr[n] = *(const short8*)&Bs[wc * 64 + n * 16 + fr][ko];
#pragma unroll
    for (int m = 0; m < 4; ++m)
#pragma unroll
      for (int n = 0; n < 4; ++n)
        acc[m][n] = __builtin_amdgcn_mfma_f32_16x16x32_bf16(af[m], bfr[n], acc[m][n], 0, 0, 0);
  }

  // epilogue: C/D layout col=lane&15, row=(lane>>4)*4+j  [verified m89/m91]
  const int qq = lane >> 4;
#pragma unroll
  for (int m = 0; m < 4; ++m) {
#pragma unroll
    for (int n = 0; n < 4; ++n) {
      const int col = (int)bcol0 + wc * 64 + n * 16 + fr;
      const bool dofm = col < fm_cols;
#pragma unroll
      for (int j = 0; j < 4; ++j) {
        const int row = (int)arow0 + wr * 64 + m * 16 + qq * 4 + j;
        float x = acc[m][n][j];
        if (dofm) x = (x > 0.f) ? x + 1.f : __expf(x);
        if constexpr (sizeof(OutT) == 2) {
          C[(size_t)row * ldc + col] = (OutT)f2bf(x);
        } else {
          C[(size_t)row * ldc + col] = x;
        }
      }
    }
  }
}

// ---------------- kv state partials: kv[bh,d,e] = sum_n k[n,d]*v[n,e] ----------------
// kvmat: [16384 rows][2048]: cols 0..1023 = fm(k) (done in GEMM epilogue), 1024..2047 = v
__global__ __launch_bounds__(256) void kv_partial(
    const unsigned short* __restrict__ kvmat, float* __restrict__ kvp,
    float* __restrict__ ksp) {
  const int blk = blockIdx.x;      // 64*SEG
  const int bh = blk >> 4;         // /SEG (SEG==16)
  const int seg = blk & (SEG - 1);
  const int b = bh >> 4, h = bh & 15;
  const int rows = 4096 / SEG;     // 256
  const size_t row0 = (size_t)b * 4096 + (size_t)seg * rows;
  const unsigned short* kb = kvmat + row0 * 2048 + h * 64;
  const unsigned short* vb = kvmat + row0 * 2048 + 1024 + h * 64;
  __shared__ float kl[32][64];
  __shared__ float vl[32][64];
  const int tid = threadIdx.x;
  const int d0 = (tid >> 4) * 4, e0 = (tid & 15) * 4;
  const int lr = tid >> 3, lc = (tid & 7) * 8;
  float accm[4][4] = {};
  float ksacc[4] = {0.f, 0.f, 0.f, 0.f};

  for (int c = 0; c < rows; c += 32) {
    __syncthreads();
    {
      const short8 k8 = *(const short8*)(kb + (size_t)(c + lr) * 2048 + lc);
      const short8 v8 = *(const short8*)(vb + (size_t)(c + lr) * 2048 + lc);
#pragma unroll
      for (int j = 0; j < 8; ++j) {
        kl[lr][lc + j] = bf2f((unsigned short)k8[j]);
        vl[lr][lc + j] = bf2f((unsigned short)v8[j]);
      }
    }
    __syncthreads();
#pragma unroll
    for (int r = 0; r < 32; ++r) {
      const f32x4 kd = *(const f32x4*)&kl[r][d0];
      const f32x4 ve = *(const f32x4*)&vl[r][e0];
#pragma unroll
      for (int i = 0; i < 4; ++i) {
        ksacc[i] += kd[i];
#pragma unroll
        for (int j = 0; j < 4; ++j) accm[i][j] += kd[i] * ve[j];
      }
    }
  }
  float* kvout = kvp + ((size_t)seg * 64 + bh) * 4096;
#pragma unroll
  for (int i = 0; i < 4; ++i) {
    f32x4 o = {accm[i][0], accm[i][1], accm[i][2], accm[i][3]};
    *(f32x4*)&kvout[(d0 + i) * 64 + e0] = o;
  }
  if ((tid & 15) == 0) {
#pragma unroll
    for (int i = 0; i < 4; ++i)
      ksp[((size_t)seg * 64 + bh) * 64 + d0 + i] = ksacc[i];
  }
}

__global__ void kv_reduce(const float* __restrict__ kvp, const float* __restrict__ ksp,
                          float* __restrict__ kv, float* __restrict__ ks) {
  const int idx = blockIdx.x * 256 + threadIdx.x;  // grid 1024 -> 262144 threads
  if (idx < 64 * 4096) {
    float s = 0.f;
    for (int g = 0; g < SEG; ++g) s += kvp[(size_t)g * 64 * 4096 + idx];
    kv[idx] = s;
  }
  if (idx < 64 * 64) {
    float s = 0.f;
    for (int g = 0; g < SEG; ++g) s += ksp[(size_t)g * 4096 + idx];
    ks[idx] = s;
  }
}

// ---------------- att[row, h*64+e] = (q . kv) / (q . ksum + 1e-6) ----------------
__global__ __launch_bounds__(256) void attn_out(
    const unsigned short* __restrict__ q, const float* __restrict__ kv,
    const float* __restrict__ ksum, unsigned short* __restrict__ att) {
  const int blk = blockIdx.x;  // 64*16
  const int bh = blk >> 4, nt = blk & 15;
  const int b = bh >> 4, h = bh & 15;
  __shared__ float kvl[4096];
  __shared__ float ksl[64];
  const int tid = threadIdx.x;
  for (int i = tid; i < 4096; i += 256) kvl[i] = kv[(size_t)bh * 4096 + i];
  if (tid < 64) ksl[tid] = ksum[bh * 64 + tid];
  __syncthreads();
  const int row = b * 4096 + nt * 256 + tid;
  const unsigned short* qrow = q + (size_t)row * 1024 + h * 64;
  float qv[64];
#pragma unroll
  for (int i = 0; i < 8; ++i) {
    const short8 s = ((const short8*)qrow)[i];
#pragma unroll
    for (int j = 0; j < 8; ++j) qv[i * 8 + j] = bf2f((unsigned short)s[j]);
  }
  float norm = 0.f;
#pragma unroll
  for (int d = 0; d < 64; ++d) norm += qv[d] * ksl[d];
  const float rn = 1.f / (norm + 1e-6f);
  unsigned short* orow = att + (size_t)row * 1024 + h * 64;
#pragma unroll 1
  for (int e0 = 0; e0 < 64; e0 += 4) {
    f32x4 a = {0.f, 0.f, 0.f, 0.f};
#pragma unroll
    for (int d = 0; d < 64; ++d) {
      const f32x4 kk = *(const f32x4*)&kvl[d * 64 + e0];
      a += qv[d] * kk;  // broadcast LDS read
    }
    a *= rn;
    ushort4_t o;
    o[0] = f2bf(a[0]); o[1] = f2bf(a[1]); o[2] = f2bf(a[2]); o[3] = f2bf(a[3]);
    *(ushort4_t*)&orow[e0] = o;
  }
}

extern "C" void kernel_launch(void* const* d_in, const int* in_sizes, int n_in,
                              void* d_out, int out_size, void* d_ws, size_t ws_size,
                              hipStream_t stream) {
  const float* x = (const float*)d_in[0];      // [4,4096,1024]
  const float* wqkv = (const float*)d_in[1];   // [3072,1024]
  const float* wout = (const float*)d_in[2];   // [1024,1024]
  float* out = (float*)d_out;                  // [4,4096,1024] fp32

  char* ws = (char*)d_ws;
  size_t off = 0;
  auto alloc = [&](size_t bytes) -> void* {
    void* p = ws + off;
    off += (bytes + 255) & ~(size_t)255;
    return p;
  };
  unsigned short* xbf    = (unsigned short*)alloc((size_t)16384 * 1024 * 2);  // 33.5 MB
  unsigned short* wqkvbf = (unsigned short*)alloc((size_t)3072 * 1024 * 2);   //  6.3 MB
  unsigned short* woutbf = (unsigned short*)alloc((size_t)1024 * 1024 * 2);   //  2.1 MB
  unsigned short* big    = (unsigned short*)alloc((size_t)16384 * 2048 * 2);  // 67.1 MB (k|v, later q+att)
  float* kvp = (float*)alloc((size_t)SEG * 64 * 4096 * 4);                    // 16.8 MB
  float* ksp = (float*)alloc((size_t)SEG * 64 * 64 * 4);
  float* kv  = (float*)alloc((size_t)64 * 4096 * 4);
  float* ks  = (float*)alloc((size_t)64 * 64 * 4);
  unsigned short* qbuf = big;                          // reuse after kv_partial consumed k,v
  unsigned short* att  = big + (size_t)16384 * 1024;   // second half of big

  cast_f32_bf16<<<2048, 256, 0, stream>>>(x, xbf, 16384 * 1024 / 4);
  cast_f32_bf16<<<1024, 256, 0, stream>>>(wqkv, wqkvbf, 3072 * 1024 / 4);
  cast_f32_bf16<<<512, 256, 0, stream>>>(wout, woutbf, 1024 * 1024 / 4);

  // GEMM1a: [k|v] = x @ w_qkv[1024:3072].T ; fm(elu+1) on k cols (<1024)
  gemm_bt<unsigned short><<<dim3(2048 / 128, 16384 / 128), 256, 0, stream>>>(
      xbf, wqkvbf + (size_t)1024 * 1024, big, 16384, 2048, 1024, 2048, 1024);

  kv_partial<<<64 * SEG, 256, 0, stream>>>(big, kvp, ksp);
  kv_reduce<<<1024, 256, 0, stream>>>(kvp, ksp, kv, ks);

  // GEMM1b: q = fm(x @ w_qkv[0:1024].T)  (overwrites dead k/v region)
  gemm_bt<unsigned short><<<dim3(1024 / 128, 16384 / 128), 256, 0, stream>>>(
      xbf, wqkvbf, qbuf, 16384, 1024, 1024, 1024, 1024);

  attn_out<<<64 * 16, 256, 0, stream>>>(qbuf, kv, ks, att);

  // GEMM2: out = att @ w_out.T (fp32 out, no fm)
  gemm_bt<float><<<dim3(1024 / 128, 16384 / 128), 256, 0, stream>>>(
      att, woutbf, out, 16384, 1024, 1024, 1024, 0);
}

// Round 2
// 348.033 us; speedup vs baseline: 1.3072x; 1.3072x over previous
//
#include <hip/hip_runtime.h>
#include <hip/hip_bf16.h>
#include <stdint.h>

typedef __attribute__((ext_vector_type(8))) short short8;
typedef __attribute__((ext_vector_type(4))) float f32x4;
typedef __attribute__((ext_vector_type(4))) unsigned short ushort4_t;

#define SEG 16

__device__ __forceinline__ float bf2f(unsigned short u) {
  unsigned int x = ((unsigned int)u) << 16;
  return __uint_as_float(x);
}
__device__ __forceinline__ unsigned short f2bf(float f) {
  unsigned int u = __float_as_uint(f);
  u += 0x7fffu + ((u >> 16) & 1u);
  return (unsigned short)(u >> 16);
}

// async global->LDS, 16B per lane, dest = wave-uniform base + lane*16
__device__ __forceinline__ void gload16(const unsigned short* g, unsigned short* l) {
  __builtin_amdgcn_global_load_lds(
      (const __attribute__((address_space(1))) void*)g,
      (__attribute__((address_space(3))) void*)l, 16, 0, 0);
}

// ---------------- cast fp32 -> bf16 (vectorized) ----------------
__global__ void cast_f32_bf16(const float* __restrict__ in,
                              unsigned short* __restrict__ out, int n4) {
  const int stride = gridDim.x * blockDim.x;
  for (int i = blockIdx.x * blockDim.x + threadIdx.x; i < n4; i += stride) {
    const float4 v = ((const float4*)in)[i];
    ushort4_t o;
    o[0] = f2bf(v.x); o[1] = f2bf(v.y); o[2] = f2bf(v.z); o[3] = f2bf(v.w);
    ((ushort4_t*)out)[i] = o;
  }
}

// ---------------- GEMM: C[M,N] = A[M,K] * B[N,K]^T  (m97 structure) ----------------
// A row-major [M,K] bf16, B row-major [N,K] bf16, C OutT.
// fm_cols: apply elu(x)+1 to output columns < fm_cols (fp32, pre-store).
// 128x128 tile, BK=32, 4 waves 2x2, global_load_lds width-16, linear LDS.
template <typename OutT>
__global__ __launch_bounds__(256) void gemm_bt(
    const unsigned short* __restrict__ A, const unsigned short* __restrict__ Bm,
    OutT* __restrict__ C, int M, int N, int K, int ldc, int fm_cols) {
  __shared__ unsigned short As[128 * 32];  // linear [row][32] (64B/row)
  __shared__ unsigned short Bs[128 * 32];
  const int tid = threadIdx.x;
  const int lane = tid & 63;
  const int wave = tid >> 6;
  const int wr = wave >> 1, wc = wave & 1;  // 2x2 wave grid, each 64x64 out
  const size_t arow0 = (size_t)blockIdx.y * 128;
  const size_t bcol0 = (size_t)blockIdx.x * 128;
  f32x4 acc[4][4] = {};
  const int l4 = lane >> 2;        // staging row-within-16 (4 lanes per 64B row)
  const int c8 = (lane & 3) * 8;   // staging elem offset 0,8,16,24
  const int fr = lane & 15;
  const int ko = (lane >> 4) * 8;
  // wave w stages rows [w*32, w*32+32): 2 issues of 1KB (16 rows each)
  const unsigned short* Ab = A + (arow0 + wave * 32 + l4) * K + c8;
  const unsigned short* Bb = Bm + (bcol0 + wave * 32 + l4) * K + c8;
  unsigned short* AsW = As + wave * 1024;  // elems (2KB per wave)
  unsigned short* BsW = Bs + wave * 1024;

  for (int k0 = 0; k0 < K; k0 += 32) {
    __syncthreads();  // previous tile fully consumed
    gload16(Ab + k0, AsW);
    gload16(Ab + 16 * K + k0, AsW + 512);
    gload16(Bb + k0, BsW);
    gload16(Bb + 16 * K + k0, BsW + 512);
    __syncthreads();  // vmcnt(0) drain + barrier: tile visible
    short8 af[4], bfv[4];
#pragma unroll
    for (int m = 0; m < 4; ++m)
      af[m] = *(const short8*)&As[(wr * 64 + m * 16 + fr) * 32 + ko];
#pragma unroll
    for (int n = 0; n < 4; ++n)
      bfv[n] = *(const short8*)&Bs[(wc * 64 + n * 16 + fr) * 32 + ko];
#pragma unroll
    for (int m = 0; m < 4; ++m)
#pragma unroll
      for (int n = 0; n < 4; ++n)
        acc[m][n] = __builtin_amdgcn_mfma_f32_16x16x32_bf16(af[m], bfv[n], acc[m][n], 0, 0, 0);
  }

  // epilogue: C/D layout col=lane&15, row=(lane>>4)*4+j  [verified m89/m91]
  const int qq = lane >> 4;
#pragma unroll
  for (int m = 0; m < 4; ++m) {
#pragma unroll
    for (int n = 0; n < 4; ++n) {
      const int col = (int)bcol0 + wc * 64 + n * 16 + fr;
      const bool dofm = col < fm_cols;
#pragma unroll
      for (int j = 0; j < 4; ++j) {
        const int row = (int)arow0 + wr * 64 + m * 16 + qq * 4 + j;
        float x = acc[m][n][j];
        if (dofm) x = (x > 0.f) ? x + 1.f : __expf(x);
        if constexpr (sizeof(OutT) == 2) {
          C[(size_t)row * ldc + col] = (OutT)f2bf(x);
        } else {
          C[(size_t)row * ldc + col] = x;
        }
      }
    }
  }
}

// ---------------- kv state partials: kv[bh,d,e] = sum_n k[n,d]*v[n,e] ----------------
// kvmat: [16384 rows][2048]: cols 0..1023 = fm(k), 1024..2047 = v
__global__ __launch_bounds__(256) void kv_partial(
    const unsigned short* __restrict__ kvmat, float* __restrict__ kvp,
    float* __restrict__ ksp) {
  const int blk = blockIdx.x;      // 64*SEG
  const int bh = blk >> 4;
  const int seg = blk & (SEG - 1);
  const int b = bh >> 4, h = bh & 15;
  const int rows = 4096 / SEG;     // 256
  const size_t row0 = (size_t)b * 4096 + (size_t)seg * rows;
  const unsigned short* kb = kvmat + row0 * 2048 + h * 64;
  const unsigned short* vb = kvmat + row0 * 2048 + 1024 + h * 64;
  __shared__ float kl[32][64];
  __shared__ float vl[32][64];
  const int tid = threadIdx.x;
  const int d0 = (tid >> 4) * 4, e0 = (tid & 15) * 4;
  const int lr = tid >> 3, lc = (tid & 7) * 8;
  float accm[4][4] = {};
  float ksacc[4] = {0.f, 0.f, 0.f, 0.f};

  for (int c = 0; c < rows; c += 32) {
    __syncthreads();
    {
      const short8 k8 = *(const short8*)(kb + (size_t)(c + lr) * 2048 + lc);
      const short8 v8 = *(const short8*)(vb + (size_t)(c + lr) * 2048 + lc);
#pragma unroll
      for (int j = 0; j < 8; ++j) {
        kl[lr][lc + j] = bf2f((unsigned short)k8[j]);
        vl[lr][lc + j] = bf2f((unsigned short)v8[j]);
      }
    }
    __syncthreads();
#pragma unroll
    for (int r = 0; r < 32; ++r) {
      const f32x4 kd = *(const f32x4*)&kl[r][d0];
      const f32x4 ve = *(const f32x4*)&vl[r][e0];
#pragma unroll
      for (int i = 0; i < 4; ++i) {
        ksacc[i] += kd[i];
#pragma unroll
        for (int j = 0; j < 4; ++j) accm[i][j] += kd[i] * ve[j];
      }
    }
  }
  float* kvout = kvp + ((size_t)seg * 64 + bh) * 4096;
#pragma unroll
  for (int i = 0; i < 4; ++i) {
    f32x4 o = {accm[i][0], accm[i][1], accm[i][2], accm[i][3]};
    *(f32x4*)&kvout[(d0 + i) * 64 + e0] = o;
  }
  if ((tid & 15) == 0) {
#pragma unroll
    for (int i = 0; i < 4; ++i)
      ksp[((size_t)seg * 64 + bh) * 64 + d0 + i] = ksacc[i];
  }
}

// reduce partials -> kvb[bh][80][64] bf16: rows e<64 = kv^T, row 64 = ksum, 65..79 = 0
__global__ void kv_reduce_bf(const float* __restrict__ kvp, const float* __restrict__ ksp,
                             unsigned short* __restrict__ kvb) {
  const int idx = blockIdx.x * 256 + threadIdx.x;  // 64*80*64
  if (idx >= 64 * 80 * 64) return;
  const int bh = idx / 5120, r = idx % 5120, e = r >> 6, d = r & 63;
  float s = 0.f;
  if (e < 64) {
    for (int g = 0; g < SEG; ++g) s += kvp[((size_t)g * 64 + bh) * 4096 + d * 64 + e];
  } else if (e == 64) {
    for (int g = 0; g < SEG; ++g) s += ksp[((size_t)g * 64 + bh) * 64 + d];
  }
  kvb[idx] = f2bf(s);
}

// ---------------- attn via MFMA: att[row, h*64+e] = (q.kv)/(q.ksum + 1e-6) ----------------
// Per block: 256 rows x 80 cols of one (b,h). B[80][64] = kvb slice (col 64 = norm).
__global__ __launch_bounds__(256) void attn_mfma(
    const unsigned short* __restrict__ q,    // [16384][1024] bf16 (fm applied)
    const unsigned short* __restrict__ kvb,  // [64][80][64] bf16
    unsigned short* __restrict__ att) {      // [16384][1024] bf16
  const int bh = blockIdx.x >> 4;
  const int rt = blockIdx.x & 15;
  const int b = bh >> 4, h = bh & 15;
  __shared__ unsigned short As[2 * 256 * 32];  // [ks][row][32]  32KB
  __shared__ unsigned short Bs[2 * 80 * 32];   // [ks][e][32]    10KB
  const int tid = threadIdx.x, lane = tid & 63, wave = tid >> 6;
  const int l4 = lane >> 2;       // 4 lanes per 64B LDS row
  const int c8 = (lane & 3) * 8;
  const size_t qrow0 = (size_t)b * 4096 + (size_t)rt * 256;
  // A stage: wave covers rows [wave*64, wave*64+64), 4 issues/slab, 2 slabs
  const unsigned short* Ab = q + (qrow0 + wave * 64 + l4) * 1024 + h * 64 + c8;
  unsigned short* AsW = As;
#pragma unroll
  for (int ks = 0; ks < 2; ++ks)
#pragma unroll
    for (int i = 0; i < 4; ++i)
      gload16(Ab + (size_t)i * 16 * 1024 + ks * 32,
              AsW + ks * 8192 + wave * 2048 + i * 512);
  // B stage: 5120 elems via short8 chunks
  for (int c = tid; c < 640; c += 256) {
    const int m0 = c * 8, ks = m0 / 2560, rr = m0 % 2560, e = rr / 32, dk = rr % 32;
    *(short8*)&Bs[m0] = *(const short8*)&kvb[(size_t)bh * 5120 + e * 64 + ks * 32 + dk];
  }
  __syncthreads();

  const int fr = lane & 15, ko = (lane >> 4) * 8;
  short8 af[4][2], bfv[5][2];
#pragma unroll
  for (int m = 0; m < 4; ++m)
#pragma unroll
    for (int ks = 0; ks < 2; ++ks)
      af[m][ks] = *(const short8*)&As[ks * 8192 + (wave * 64 + m * 16 + fr) * 32 + ko];
#pragma unroll
  for (int n = 0; n < 5; ++n)
#pragma unroll
    for (int ks = 0; ks < 2; ++ks)
      bfv[n][ks] = *(const short8*)&Bs[ks * 2560 + (n * 16 + fr) * 32 + ko];
  f32x4 acc[4][5] = {};
#pragma unroll
  for (int m = 0; m < 4; ++m)
#pragma unroll
    for (int n = 0; n < 5; ++n) {
      acc[m][n] = __builtin_amdgcn_mfma_f32_16x16x32_bf16(af[m][0], bfv[n][0], acc[m][n], 0, 0, 0);
      acc[m][n] = __builtin_amdgcn_mfma_f32_16x16x32_bf16(af[m][1], bfv[n][1], acc[m][n], 0, 0, 0);
    }

  // epilogue: norm = col 64 (n-tile 4, fr==0 lane of each 16-lane group)
  const int qq = lane >> 4;
#pragma unroll
  for (int m = 0; m < 4; ++m) {
    f32x4 rnv;
#pragma unroll
    for (int j = 0; j < 4; ++j) {
      const float nv = __shfl(acc[m][4][j], lane & 48);
      rnv[j] = 1.f / (nv + 1e-6f);
    }
    const size_t row = qrow0 + wave * 64 + m * 16 + qq * 4;
#pragma unroll
    for (int n = 0; n < 4; ++n)
#pragma unroll
      for (int j = 0; j < 4; ++j)
        att[(row + j) * 1024 + h * 64 + n * 16 + fr] = f2bf(acc[m][n][j] * rnv[j]);
  }
}

extern "C" void kernel_launch(void* const* d_in, const int* in_sizes, int n_in,
                              void* d_out, int out_size, void* d_ws, size_t ws_size,
                              hipStream_t stream) {
  const float* x = (const float*)d_in[0];      // [4,4096,1024]
  const float* wqkv = (const float*)d_in[1];   // [3072,1024]
  const float* wout = (const float*)d_in[2];   // [1024,1024]
  float* out = (float*)d_out;                  // [4,4096,1024] fp32

  char* ws = (char*)d_ws;
  size_t off = 0;
  auto alloc = [&](size_t bytes) -> void* {
    void* p = ws + off;
    off += (bytes + 255) & ~(size_t)255;
    return p;
  };
  unsigned short* xbf    = (unsigned short*)alloc((size_t)16384 * 1024 * 2);  // 33.5 MB
  unsigned short* wqkvbf = (unsigned short*)alloc((size_t)3072 * 1024 * 2);   //  6.3 MB
  unsigned short* woutbf = (unsigned short*)alloc((size_t)1024 * 1024 * 2);   //  2.1 MB
  unsigned short* big    = (unsigned short*)alloc((size_t)16384 * 2048 * 2);  // 67.1 MB (k|v, later q+att)
  float* kvp = (float*)alloc((size_t)SEG * 64 * 4096 * 4);                    // 16.8 MB
  float* ksp = (float*)alloc((size_t)SEG * 64 * 64 * 4);
  unsigned short* kvb = (unsigned short*)alloc((size_t)64 * 80 * 64 * 2);     // 0.66 MB
  unsigned short* qbuf = big;                          // reuse after kv_partial consumed k,v
  unsigned short* att  = big + (size_t)16384 * 1024;   // second half of big

  cast_f32_bf16<<<2048, 256, 0, stream>>>(x, xbf, 16384 * 1024 / 4);
  cast_f32_bf16<<<1024, 256, 0, stream>>>(wqkv, wqkvbf, 3072 * 1024 / 4);
  cast_f32_bf16<<<512, 256, 0, stream>>>(wout, woutbf, 1024 * 1024 / 4);

  // GEMM1a: [k|v] = x @ w_qkv[1024:3072].T ; fm on k cols (<1024)
  gemm_bt<unsigned short><<<dim3(2048 / 128, 16384 / 128), 256, 0, stream>>>(
      xbf, wqkvbf + (size_t)1024 * 1024, big, 16384, 2048, 1024, 2048, 1024);

  kv_partial<<<64 * SEG, 256, 0, stream>>>(big, kvp, ksp);
  kv_reduce_bf<<<1280, 256, 0, stream>>>(kvp, ksp, kvb);

  // GEMM1b: q = fm(x @ w_qkv[0:1024].T)  (overwrites dead k/v region)
  gemm_bt<unsigned short><<<dim3(1024 / 128, 16384 / 128), 256, 0, stream>>>(
      xbf, wqkvbf, qbuf, 16384, 1024, 1024, 1024, 1024);

  attn_mfma<<<64 * 16, 256, 0, stream>>>(qbuf, kvb, att);

  // GEMM2: out = att @ w_out.T (fp32 out, no fm)
  gemm_bt<float><<<dim3(1024 / 128, 16384 / 128), 256, 0, stream>>>(
      att, woutbf, out, 16384, 1024, 1024, 1024, 0);
}

// Round 3
// 276.874 us; speedup vs baseline: 1.6432x; 1.2570x over previous
//
#include <hip/hip_runtime.h>
#include <hip/hip_bf16.h>
#include <stdint.h>

typedef __attribute__((ext_vector_type(8))) short short8;
typedef __attribute__((ext_vector_type(4))) float f32x4;
typedef __attribute__((ext_vector_type(4))) unsigned short ushort4_t;

#define SEG 16

__device__ __forceinline__ float bf2f(unsigned short u) {
  unsigned int x = ((unsigned int)u) << 16;
  return __uint_as_float(x);
}
__device__ __forceinline__ unsigned short f2bf(float f) {
  unsigned int u = __float_as_uint(f);
  u += 0x7fffu + ((u >> 16) & 1u);
  return (unsigned short)(u >> 16);
}

// async global->LDS, 16B per lane, dest = wave-uniform base + lane*16
__device__ __forceinline__ void gload16(const unsigned short* g, unsigned short* l) {
  __builtin_amdgcn_global_load_lds(
      (const __attribute__((address_space(1))) void*)g,
      (__attribute__((address_space(3))) void*)l, 16, 0, 0);
}

// ---------------- cast fp32 -> bf16 (vectorized) ----------------
__global__ void cast_f32_bf16(const float* __restrict__ in,
                              unsigned short* __restrict__ out, int n4) {
  const int stride = gridDim.x * blockDim.x;
  for (int i = blockIdx.x * blockDim.x + threadIdx.x; i < n4; i += stride) {
    const float4 v = ((const float4*)in)[i];
    ushort4_t o;
    o[0] = f2bf(v.x); o[1] = f2bf(v.y); o[2] = f2bf(v.z); o[3] = f2bf(v.w);
    ((ushort4_t*)out)[i] = o;
  }
}

// ---------------- GEMM 256x256, BK=32, triple-buffer counted-vmcnt pipeline ----
// C[M,N] = A[M,K] * B[N,K]^T. 512 threads = 8 waves (2 M x 4 N), per-wave 128x64.
// LDS: 3 slots x (A 256x32 + B 256x32) = 96KB. Chunk-XOR swizzle (both-sides).
// Pipeline invariant at iter t's end barrier: own loads beyond 4 drained ->
// tile t+1 globally staged; tile t+2's 4 loads/wave remain in flight (vmcnt(4)).
template <typename OutT>
__global__ __launch_bounds__(512, 2) void gemm256(
    const unsigned short* __restrict__ A, const unsigned short* __restrict__ Bm,
    OutT* __restrict__ C, int M, int N, int K, int ldc, int fm_cols) {
  __shared__ unsigned short lds[3 * 16384];  // slot: A[256][32] @0, B[256][32] @8192
  const int tid = threadIdx.x;
  const int lane = tid & 63;
  const int w = tid >> 6;                    // wave 0..7
  const int wr = w >> 2, wc = w & 3;         // 2x4 wave grid; wave out = 128x64
  const size_t arow0 = (size_t)blockIdx.y * 256;
  const size_t bcol0 = (size_t)blockIdx.x * 256;
  const int nt = K >> 5;

  // staging geometry: 16 segments of 16 rows per matrix; wave w stages segs {w, w+8}
  const int rseg = lane >> 2;                           // row within segment
  const int sc = (((lane & 3) ^ (rseg & 3)) << 3);      // pre-swizzled source elem off
  const unsigned short* Aseg0 = A + (arow0 + w * 16 + rseg) * K + sc;
  const unsigned short* Aseg1 = A + (arow0 + (w + 8) * 16 + rseg) * K + sc;
  const unsigned short* Bseg0 = Bm + (bcol0 + w * 16 + rseg) * K + sc;
  const unsigned short* Bseg1 = Bm + (bcol0 + (w + 8) * 16 + rseg) * K + sc;

  auto stage = [&](int kt, int slot) {
    const int k0 = kt << 5;
    unsigned short* buf = lds + slot * 16384;
    gload16(Aseg0 + k0, buf + w * 512);
    gload16(Aseg1 + k0, buf + (w + 8) * 512);
    gload16(Bseg0 + k0, buf + 8192 + w * 512);
    gload16(Bseg1 + k0, buf + 8192 + (w + 8) * 512);
  };

  f32x4 acc[8][4] = {};
  const int fr = lane & 15;        // fragment row/col
  const int kc = lane >> 4;        // k-chunk index 0..3 (octet = kc*8)

  stage(0, 0);
  stage(1, 1);
  asm volatile("s_waitcnt vmcnt(4)" ::: "memory");
  __builtin_amdgcn_s_barrier();
  __builtin_amdgcn_sched_barrier(0);

  for (int t = 0; t < nt; ++t) {
    const int nx = (t + 2 < nt) ? t + 2 : t + 2 - nt;  // wrap = harmless dummy restage
    stage(nx, (t + 2) % 3);
    const unsigned short* buf = lds + (t % 3) * 16384;
    short8 af[8], bfv[4];
#pragma unroll
    for (int m = 0; m < 8; ++m) {
      const int r = wr * 128 + m * 16 + fr;
      af[m] = *(const short8*)&buf[r * 32 + ((kc ^ (r & 3)) << 3)];
    }
#pragma unroll
    for (int n = 0; n < 4; ++n) {
      const int r = wc * 64 + n * 16 + fr;
      bfv[n] = *(const short8*)&buf[8192 + r * 32 + ((kc ^ (r & 3)) << 3)];
    }
    __builtin_amdgcn_s_setprio(1);
#pragma unroll
    for (int m = 0; m < 8; ++m)
#pragma unroll
      for (int n = 0; n < 4; ++n)
        acc[m][n] = __builtin_amdgcn_mfma_f32_16x16x32_bf16(af[m], bfv[n], acc[m][n], 0, 0, 0);
    __builtin_amdgcn_s_setprio(0);
    asm volatile("s_waitcnt vmcnt(4)" ::: "memory");
    __builtin_amdgcn_s_barrier();
    __builtin_amdgcn_sched_barrier(0);
  }

  // epilogue: C/D layout col=lane&15, row=(lane>>4)*4+j  [verified m89/m91]
  const int qq = lane >> 4;
#pragma unroll
  for (int m = 0; m < 8; ++m) {
#pragma unroll
    for (int n = 0; n < 4; ++n) {
      const int col = (int)bcol0 + wc * 64 + n * 16 + fr;
      const bool dofm = col < fm_cols;
#pragma unroll
      for (int j = 0; j < 4; ++j) {
        const int row = (int)arow0 + wr * 128 + m * 16 + qq * 4 + j;
        float x = acc[m][n][j];
        if (dofm) x = (x > 0.f) ? x + 1.f : __expf(x);
        if constexpr (sizeof(OutT) == 2) {
          C[(size_t)row * ldc + col] = (OutT)f2bf(x);
        } else {
          C[(size_t)row * ldc + col] = x;
        }
      }
    }
  }
}

// ---------------- kv state partials: kv[bh,d,e] = sum_n k[n,d]*v[n,e] ----------------
// kvmat: [16384 rows][2048]: cols 0..1023 = fm(k), 1024..2047 = v
__global__ __launch_bounds__(256) void kv_partial(
    const unsigned short* __restrict__ kvmat, float* __restrict__ kvp,
    float* __restrict__ ksp) {
  const int blk = blockIdx.x;      // 64*SEG
  const int bh = blk >> 4;
  const int seg = blk & (SEG - 1);
  const int b = bh >> 4, h = bh & 15;
  const int rows = 4096 / SEG;     // 256
  const size_t row0 = (size_t)b * 4096 + (size_t)seg * rows;
  const unsigned short* kb = kvmat + row0 * 2048 + h * 64;
  const unsigned short* vb = kvmat + row0 * 2048 + 1024 + h * 64;
  __shared__ float kl[32][64];
  __shared__ float vl[32][64];
  const int tid = threadIdx.x;
  const int d0 = (tid >> 4) * 4, e0 = (tid & 15) * 4;
  const int lr = tid >> 3, lc = (tid & 7) * 8;
  float accm[4][4] = {};
  float ksacc[4] = {0.f, 0.f, 0.f, 0.f};

  for (int c = 0; c < rows; c += 32) {
    __syncthreads();
    {
      const short8 k8 = *(const short8*)(kb + (size_t)(c + lr) * 2048 + lc);
      const short8 v8 = *(const short8*)(vb + (size_t)(c + lr) * 2048 + lc);
#pragma unroll
      for (int j = 0; j < 8; ++j) {
        kl[lr][lc + j] = bf2f((unsigned short)k8[j]);
        vl[lr][lc + j] = bf2f((unsigned short)v8[j]);
      }
    }
    __syncthreads();
#pragma unroll
    for (int r = 0; r < 32; ++r) {
      const f32x4 kd = *(const f32x4*)&kl[r][d0];
      const f32x4 ve = *(const f32x4*)&vl[r][e0];
#pragma unroll
      for (int i = 0; i < 4; ++i) {
        ksacc[i] += kd[i];
#pragma unroll
        for (int j = 0; j < 4; ++j) accm[i][j] += kd[i] * ve[j];
      }
    }
  }
  float* kvout = kvp + ((size_t)seg * 64 + bh) * 4096;
#pragma unroll
  for (int i = 0; i < 4; ++i) {
    f32x4 o = {accm[i][0], accm[i][1], accm[i][2], accm[i][3]};
    *(f32x4*)&kvout[(d0 + i) * 64 + e0] = o;
  }
  if ((tid & 15) == 0) {
#pragma unroll
    for (int i = 0; i < 4; ++i)
      ksp[((size_t)seg * 64 + bh) * 64 + d0 + i] = ksacc[i];
  }
}

// reduce partials -> kvb[bh][80][64] bf16: rows e<64 = kv^T, row 64 = ksum, 65..79 = 0
__global__ void kv_reduce_bf(const float* __restrict__ kvp, const float* __restrict__ ksp,
                             unsigned short* __restrict__ kvb) {
  const int idx = blockIdx.x * 256 + threadIdx.x;  // 64*80*64
  if (idx >= 64 * 80 * 64) return;
  const int bh = idx / 5120, r = idx % 5120, e = r >> 6, d = r & 63;
  float s = 0.f;
  if (e < 64) {
    for (int g = 0; g < SEG; ++g) s += kvp[((size_t)g * 64 + bh) * 4096 + d * 64 + e];
  } else if (e == 64) {
    for (int g = 0; g < SEG; ++g) s += ksp[((size_t)g * 64 + bh) * 64 + d];
  }
  kvb[idx] = f2bf(s);
}

// ---------------- attn via MFMA: att[row, h*64+e] = (q.kv)/(q.ksum + 1e-6) ----------------
__global__ __launch_bounds__(256) void attn_mfma(
    const unsigned short* __restrict__ q,    // [16384][1024] bf16 (fm applied)
    const unsigned short* __restrict__ kvb,  // [64][80][64] bf16
    unsigned short* __restrict__ att) {      // [16384][1024] bf16
  const int bh = blockIdx.x >> 4;
  const int rt = blockIdx.x & 15;
  const int b = bh >> 4, h = bh & 15;
  __shared__ unsigned short As[2 * 256 * 32];  // [ks][row][32]  32KB
  __shared__ unsigned short Bs[2 * 80 * 32];   // [ks][e][32]    10KB
  const int tid = threadIdx.x, lane = tid & 63, wave = tid >> 6;
  const int l4 = lane >> 2;
  const int c8 = (lane & 3) * 8;
  const size_t qrow0 = (size_t)b * 4096 + (size_t)rt * 256;
  const unsigned short* Ab = q + (qrow0 + wave * 64 + l4) * 1024 + h * 64 + c8;
  unsigned short* AsW = As;
#pragma unroll
  for (int ks = 0; ks < 2; ++ks)
#pragma unroll
    for (int i = 0; i < 4; ++i)
      gload16(Ab + (size_t)i * 16 * 1024 + ks * 32,
              AsW + ks * 8192 + wave * 2048 + i * 512);
  for (int c = tid; c < 640; c += 256) {
    const int m0 = c * 8, ks = m0 / 2560, rr = m0 % 2560, e = rr / 32, dk = rr % 32;
    *(short8*)&Bs[m0] = *(const short8*)&kvb[(size_t)bh * 5120 + e * 64 + ks * 32 + dk];
  }
  __syncthreads();

  const int fr = lane & 15, ko = (lane >> 4) * 8;
  short8 af[4][2], bfv[5][2];
#pragma unroll
  for (int m = 0; m < 4; ++m)
#pragma unroll
    for (int ks = 0; ks < 2; ++ks)
      af[m][ks] = *(const short8*)&As[ks * 8192 + (wave * 64 + m * 16 + fr) * 32 + ko];
#pragma unroll
  for (int n = 0; n < 5; ++n)
#pragma unroll
    for (int ks = 0; ks < 2; ++ks)
      bfv[n][ks] = *(const short8*)&Bs[ks * 2560 + (n * 16 + fr) * 32 + ko];
  f32x4 acc[4][5] = {};
#pragma unroll
  for (int m = 0; m < 4; ++m)
#pragma unroll
    for (int n = 0; n < 5; ++n) {
      acc[m][n] = __builtin_amdgcn_mfma_f32_16x16x32_bf16(af[m][0], bfv[n][0], acc[m][n], 0, 0, 0);
      acc[m][n] = __builtin_amdgcn_mfma_f32_16x16x32_bf16(af[m][1], bfv[n][1], acc[m][n], 0, 0, 0);
    }

  const int qq = lane >> 4;
#pragma unroll
  for (int m = 0; m < 4; ++m) {
    f32x4 rnv;
#pragma unroll
    for (int j = 0; j < 4; ++j) {
      const float nv = __shfl(acc[m][4][j], lane & 48);
      rnv[j] = 1.f / (nv + 1e-6f);
    }
    const size_t row = qrow0 + wave * 64 + m * 16 + qq * 4;
#pragma unroll
    for (int n = 0; n < 4; ++n)
#pragma unroll
      for (int j = 0; j < 4; ++j)
        att[(row + j) * 1024 + h * 64 + n * 16 + fr] = f2bf(acc[m][n][j] * rnv[j]);
  }
}

extern "C" void kernel_launch(void* const* d_in, const int* in_sizes, int n_in,
                              void* d_out, int out_size, void* d_ws, size_t ws_size,
                              hipStream_t stream) {
  const float* x = (const float*)d_in[0];      // [4,4096,1024]
  const float* wqkv = (const float*)d_in[1];   // [3072,1024]
  const float* wout = (const float*)d_in[2];   // [1024,1024]
  float* out = (float*)d_out;                  // [4,4096,1024] fp32

  char* ws = (char*)d_ws;
  size_t off = 0;
  auto alloc = [&](size_t bytes) -> void* {
    void* p = ws + off;
    off += (bytes + 255) & ~(size_t)255;
    return p;
  };
  unsigned short* xbf    = (unsigned short*)alloc((size_t)16384 * 1024 * 2);  // 33.5 MB
  unsigned short* wqkvbf = (unsigned short*)alloc((size_t)3072 * 1024 * 2);   //  6.3 MB
  unsigned short* woutbf = (unsigned short*)alloc((size_t)1024 * 1024 * 2);   //  2.1 MB
  unsigned short* big    = (unsigned short*)alloc((size_t)16384 * 2048 * 2);  // 67.1 MB (k|v, later q+att)
  float* kvp = (float*)alloc((size_t)SEG * 64 * 4096 * 4);                    // 16.8 MB
  float* ksp = (float*)alloc((size_t)SEG * 64 * 64 * 4);
  unsigned short* kvb = (unsigned short*)alloc((size_t)64 * 80 * 64 * 2);     // 0.66 MB
  unsigned short* qbuf = big;                          // reuse after kv_partial consumed k,v
  unsigned short* att  = big + (size_t)16384 * 1024;   // second half of big

  cast_f32_bf16<<<2048, 256, 0, stream>>>(x, xbf, 16384 * 1024 / 4);
  cast_f32_bf16<<<1024, 256, 0, stream>>>(wqkv, wqkvbf, 3072 * 1024 / 4);
  cast_f32_bf16<<<512, 256, 0, stream>>>(wout, woutbf, 1024 * 1024 / 4);

  // GEMM1a: [k|v] = x @ w_qkv[1024:3072].T ; fm on k cols (<1024)
  gemm256<unsigned short><<<dim3(2048 / 256, 16384 / 256), 512, 0, stream>>>(
      xbf, wqkvbf + (size_t)1024 * 1024, big, 16384, 2048, 1024, 2048, 1024);

  kv_partial<<<64 * SEG, 256, 0, stream>>>(big, kvp, ksp);
  kv_reduce_bf<<<1280, 256, 0, stream>>>(kvp, ksp, kvb);

  // GEMM1b: q = fm(x @ w_qkv[0:1024].T)  (overwrites dead k/v region)
  gemm256<unsigned short><<<dim3(1024 / 256, 16384 / 256), 512, 0, stream>>>(
      xbf, wqkvbf, qbuf, 16384, 1024, 1024, 1024, 1024);

  attn_mfma<<<64 * 16, 256, 0, stream>>>(qbuf, kvb, att);

  // GEMM2: out = att @ w_out.T (fp32 out, no fm)
  gemm256<float><<<dim3(1024 / 256, 16384 / 256), 512, 0, stream>>>(
      att, woutbf, out, 16384, 1024, 1024, 1024, 0);
}

// Round 4
// 268.101 us; speedup vs baseline: 1.6969x; 1.0327x over previous
//
#include <hip/hip_runtime.h>
#include <hip/hip_bf16.h>
#include <stdint.h>

typedef __attribute__((ext_vector_type(8))) short short8;
typedef __attribute__((ext_vector_type(4))) float f32x4;
typedef __attribute__((ext_vector_type(4))) unsigned short ushort4_t;

#define SEG 16

__device__ __forceinline__ float bf2f(unsigned short u) {
  unsigned int x = ((unsigned int)u) << 16;
  return __uint_as_float(x);
}
__device__ __forceinline__ unsigned short f2bf(float f) {
  unsigned int u = __float_as_uint(f);
  u += 0x7fffu + ((u >> 16) & 1u);
  return (unsigned short)(u >> 16);
}

// async global->LDS, 16B per lane, dest = wave-uniform base + lane*16
__device__ __forceinline__ void gload16(const unsigned short* g, unsigned short* l) {
  __builtin_amdgcn_global_load_lds(
      (const __attribute__((address_space(1))) void*)g,
      (__attribute__((address_space(3))) void*)l, 16, 0, 0);
}

// ---------------- cast fp32 -> bf16 (vectorized) ----------------
__global__ void cast_f32_bf16(const float* __restrict__ in,
                              unsigned short* __restrict__ out, int n4) {
  const int stride = gridDim.x * blockDim.x;
  for (int i = blockIdx.x * blockDim.x + threadIdx.x; i < n4; i += stride) {
    const float4 v = ((const float4*)in)[i];
    ushort4_t o;
    o[0] = f2bf(v.x); o[1] = f2bf(v.y); o[2] = f2bf(v.z); o[3] = f2bf(v.w);
    ((ushort4_t*)out)[i] = o;
  }
}

// ---------------- GEMM 256x256, BK=32, quad-buffer counted-vmcnt pipeline ----
// C[M,N] = A[M,K] * B[N,K]^T. 512 threads = 8 waves (2 M x 4 N), per-wave 128x64.
// LDS: 4 slots x (A 256x32 + B 256x32) = 128KB. Chunk-XOR swizzle (both-sides).
// XCD-aware bijective blockIdx swizzle (y-major chunks -> same-XCD panel reuse).
// Invariant at iter t's end barrier: own loads beyond 8 drained -> tile t+1
// globally staged; tiles t+2,t+3 (8 loads/wave) stay in flight (vmcnt(8)).
// Slot (t+3)&3 staged at iter t was last read at iter t-1 (barrier-protected).
template <typename OutT>
__global__ __launch_bounds__(512, 2) void gemm256(
    const unsigned short* __restrict__ A, const unsigned short* __restrict__ Bm,
    OutT* __restrict__ C, int M, int N, int K, int ldc, int fm_cols) {
  __shared__ unsigned short lds[4 * 16384];  // slot: A[256][32] @0, B[256][32] @8192
  const int tid = threadIdx.x;
  const int lane = tid & 63;
  const int w = tid >> 6;                    // wave 0..7
  const int wr = w >> 2, wc = w & 3;         // 2x4 wave grid; wave out = 128x64
  // XCD-aware bijective swizzle (requires nwg % 8 == 0; all our grids qualify)
  const int gx = gridDim.x;
  const int nwg = gx * gridDim.y;
  const int hwid = blockIdx.y * gx + blockIdx.x;
  const int cpx = nwg >> 3;
  const int L = (hwid & 7) * cpx + (hwid >> 3);  // y-major logical index
  const int bx = L % gx, by = L / gx;
  const size_t arow0 = (size_t)by * 256;
  const size_t bcol0 = (size_t)bx * 256;
  const int nt = K >> 5;

  // staging geometry: 16 segments of 16 rows per matrix; wave w stages segs {w, w+8}
  const int rseg = lane >> 2;                           // row within segment
  const int sc = (((lane & 3) ^ (rseg & 3)) << 3);      // pre-swizzled source elem off
  const unsigned short* Aseg0 = A + (arow0 + w * 16 + rseg) * K + sc;
  const unsigned short* Aseg1 = A + (arow0 + (w + 8) * 16 + rseg) * K + sc;
  const unsigned short* Bseg0 = Bm + (bcol0 + w * 16 + rseg) * K + sc;
  const unsigned short* Bseg1 = Bm + (bcol0 + (w + 8) * 16 + rseg) * K + sc;

  auto stage = [&](int kt, int slot) {
    const int k0 = kt << 5;
    unsigned short* buf = lds + slot * 16384;
    gload16(Aseg0 + k0, buf + w * 512);
    gload16(Aseg1 + k0, buf + (w + 8) * 512);
    gload16(Bseg0 + k0, buf + 8192 + w * 512);
    gload16(Bseg1 + k0, buf + 8192 + (w + 8) * 512);
  };

  f32x4 acc[8][4] = {};
  const int fr = lane & 15;        // fragment row/col
  const int kc = lane >> 4;        // k-chunk index 0..3 (octet = kc*8)

  stage(0, 0);
  stage(1, 1);
  stage(2, 2);
  asm volatile("s_waitcnt vmcnt(8)" ::: "memory");
  __builtin_amdgcn_s_barrier();
  __builtin_amdgcn_sched_barrier(0);

  for (int t = 0; t < nt; ++t) {
    const int nx = (t + 3 < nt) ? t + 3 : t + 3 - nt;  // wrap = harmless dummy restage
    stage(nx, (t + 3) & 3);
    const unsigned short* buf = lds + (t & 3) * 16384;
    short8 af[8], bfv[4];
#pragma unroll
    for (int m = 0; m < 8; ++m) {
      const int r = wr * 128 + m * 16 + fr;
      af[m] = *(const short8*)&buf[r * 32 + ((kc ^ (r & 3)) << 3)];
    }
#pragma unroll
    for (int n = 0; n < 4; ++n) {
      const int r = wc * 64 + n * 16 + fr;
      bfv[n] = *(const short8*)&buf[8192 + r * 32 + ((kc ^ (r & 3)) << 3)];
    }
    __builtin_amdgcn_s_setprio(1);
#pragma unroll
    for (int m = 0; m < 8; ++m)
#pragma unroll
      for (int n = 0; n < 4; ++n)
        acc[m][n] = __builtin_amdgcn_mfma_f32_16x16x32_bf16(af[m], bfv[n], acc[m][n], 0, 0, 0);
    __builtin_amdgcn_s_setprio(0);
    asm volatile("s_waitcnt vmcnt(8)" ::: "memory");
    __builtin_amdgcn_s_barrier();
    __builtin_amdgcn_sched_barrier(0);
  }

  // epilogue: C/D layout col=lane&15, row=(lane>>4)*4+j  [verified m89/m91]
  const int qq = lane >> 4;
#pragma unroll
  for (int m = 0; m < 8; ++m) {
#pragma unroll
    for (int n = 0; n < 4; ++n) {
      const int col = (int)bcol0 + wc * 64 + n * 16 + fr;
      const bool dofm = col < fm_cols;
#pragma unroll
      for (int j = 0; j < 4; ++j) {
        const int row = (int)arow0 + wr * 128 + m * 16 + qq * 4 + j;
        float x = acc[m][n][j];
        if (dofm) x = (x > 0.f) ? x + 1.f : __expf(x);
        if constexpr (sizeof(OutT) == 2) {
          C[(size_t)row * ldc + col] = (OutT)f2bf(x);
        } else {
          C[(size_t)row * ldc + col] = x;
        }
      }
    }
  }
}

// ---------------- kv state partials: kv[bh,d,e] = sum_n k[n,d]*v[n,e] ----------------
// kvmat: [16384 rows][2048]: cols 0..1023 = fm(k), 1024..2047 = v
__global__ __launch_bounds__(256) void kv_partial(
    const unsigned short* __restrict__ kvmat, float* __restrict__ kvp,
    float* __restrict__ ksp) {
  const int blk = blockIdx.x;      // 64*SEG
  const int bh = blk >> 4;
  const int seg = blk & (SEG - 1);
  const int b = bh >> 4, h = bh & 15;
  const int rows = 4096 / SEG;     // 256
  const size_t row0 = (size_t)b * 4096 + (size_t)seg * rows;
  const unsigned short* kb = kvmat + row0 * 2048 + h * 64;
  const unsigned short* vb = kvmat + row0 * 2048 + 1024 + h * 64;
  __shared__ float kl[32][64];
  __shared__ float vl[32][64];
  const int tid = threadIdx.x;
  const int d0 = (tid >> 4) * 4, e0 = (tid & 15) * 4;
  const int lr = tid >> 3, lc = (tid & 7) * 8;
  float accm[4][4] = {};
  float ksacc[4] = {0.f, 0.f, 0.f, 0.f};

  for (int c = 0; c < rows; c += 32) {
    __syncthreads();
    {
      const short8 k8 = *(const short8*)(kb + (size_t)(c + lr) * 2048 + lc);
      const short8 v8 = *(const short8*)(vb + (size_t)(c + lr) * 2048 + lc);
#pragma unroll
      for (int j = 0; j < 8; ++j) {
        kl[lr][lc + j] = bf2f((unsigned short)k8[j]);
        vl[lr][lc + j] = bf2f((unsigned short)v8[j]);
      }
    }
    __syncthreads();
#pragma unroll
    for (int r = 0; r < 32; ++r) {
      const f32x4 kd = *(const f32x4*)&kl[r][d0];
      const f32x4 ve = *(const f32x4*)&vl[r][e0];
#pragma unroll
      for (int i = 0; i < 4; ++i) {
        ksacc[i] += kd[i];
#pragma unroll
        for (int j = 0; j < 4; ++j) accm[i][j] += kd[i] * ve[j];
      }
    }
  }
  float* kvout = kvp + ((size_t)seg * 64 + bh) * 4096;
#pragma unroll
  for (int i = 0; i < 4; ++i) {
    f32x4 o = {accm[i][0], accm[i][1], accm[i][2], accm[i][3]};
    *(f32x4*)&kvout[(d0 + i) * 64 + e0] = o;
  }
  if ((tid & 15) == 0) {
#pragma unroll
    for (int i = 0; i < 4; ++i)
      ksp[((size_t)seg * 64 + bh) * 64 + d0 + i] = ksacc[i];
  }
}

// reduce partials -> kvb[bh][80][64] bf16: rows e<64 = kv^T, row 64 = ksum, 65..79 = 0
__global__ void kv_reduce_bf(const float* __restrict__ kvp, const float* __restrict__ ksp,
                             unsigned short* __restrict__ kvb) {
  const int idx = blockIdx.x * 256 + threadIdx.x;  // 64*80*64
  if (idx >= 64 * 80 * 64) return;
  const int bh = idx / 5120, r = idx % 5120, e = r >> 6, d = r & 63;
  float s = 0.f;
  if (e < 64) {
    for (int g = 0; g < SEG; ++g) s += kvp[((size_t)g * 64 + bh) * 4096 + d * 64 + e];
  } else if (e == 64) {
    for (int g = 0; g < SEG; ++g) s += ksp[((size_t)g * 64 + bh) * 64 + d];
  }
  kvb[idx] = f2bf(s);
}

// ---------------- attn via MFMA: att[row, h*64+e] = (q.kv)/(q.ksum + 1e-6) ----------------
__global__ __launch_bounds__(256) void attn_mfma(
    const unsigned short* __restrict__ q,    // [16384][1024] bf16 (fm applied)
    const unsigned short* __restrict__ kvb,  // [64][80][64] bf16
    unsigned short* __restrict__ att) {      // [16384][1024] bf16
  const int bh = blockIdx.x >> 4;
  const int rt = blockIdx.x & 15;
  const int b = bh >> 4, h = bh & 15;
  __shared__ unsigned short As[2 * 256 * 32];  // [ks][row][32]  32KB
  __shared__ unsigned short Bs[2 * 80 * 32];   // [ks][e][32]    10KB
  const int tid = threadIdx.x, lane = tid & 63, wave = tid >> 6;
  const int l4 = lane >> 2;
  const int c8 = (lane & 3) * 8;
  const size_t qrow0 = (size_t)b * 4096 + (size_t)rt * 256;
  const unsigned short* Ab = q + (qrow0 + wave * 64 + l4) * 1024 + h * 64 + c8;
  unsigned short* AsW = As;
#pragma unroll
  for (int ks = 0; ks < 2; ++ks)
#pragma unroll
    for (int i = 0; i < 4; ++i)
      gload16(Ab + (size_t)i * 16 * 1024 + ks * 32,
              AsW + ks * 8192 + wave * 2048 + i * 512);
  for (int c = tid; c < 640; c += 256) {
    const int m0 = c * 8, ks = m0 / 2560, rr = m0 % 2560, e = rr / 32, dk = rr % 32;
    *(short8*)&Bs[m0] = *(const short8*)&kvb[(size_t)bh * 5120 + e * 64 + ks * 32 + dk];
  }
  __syncthreads();

  const int fr = lane & 15, ko = (lane >> 4) * 8;
  short8 af[4][2], bfv[5][2];
#pragma unroll
  for (int m = 0; m < 4; ++m)
#pragma unroll
    for (int ks = 0; ks < 2; ++ks)
      af[m][ks] = *(const short8*)&As[ks * 8192 + (wave * 64 + m * 16 + fr) * 32 + ko];
#pragma unroll
  for (int n = 0; n < 5; ++n)
#pragma unroll
    for (int ks = 0; ks < 2; ++ks)
      bfv[n][ks] = *(const short8*)&Bs[ks * 2560 + (n * 16 + fr) * 32 + ko];
  f32x4 acc[4][5] = {};
#pragma unroll
  for (int m = 0; m < 4; ++m)
#pragma unroll
    for (int n = 0; n < 5; ++n) {
      acc[m][n] = __builtin_amdgcn_mfma_f32_16x16x32_bf16(af[m][0], bfv[n][0], acc[m][n], 0, 0, 0);
      acc[m][n] = __builtin_amdgcn_mfma_f32_16x16x32_bf16(af[m][1], bfv[n][1], acc[m][n], 0, 0, 0);
    }

  const int qq = lane >> 4;
#pragma unroll
  for (int m = 0; m < 4; ++m) {
    f32x4 rnv;
#pragma unroll
    for (int j = 0; j < 4; ++j) {
      const float nv = __shfl(acc[m][4][j], lane & 48);
      rnv[j] = 1.f / (nv + 1e-6f);
    }
    const size_t row = qrow0 + wave * 64 + m * 16 + qq * 4;
#pragma unroll
    for (int n = 0; n < 4; ++n)
#pragma unroll
      for (int j = 0; j < 4; ++j)
        att[(row + j) * 1024 + h * 64 + n * 16 + fr] = f2bf(acc[m][n][j] * rnv[j]);
  }
}

extern "C" void kernel_launch(void* const* d_in, const int* in_sizes, int n_in,
                              void* d_out, int out_size, void* d_ws, size_t ws_size,
                              hipStream_t stream) {
  const float* x = (const float*)d_in[0];      // [4,4096,1024]
  const float* wqkv = (const float*)d_in[1];   // [3072,1024]
  const float* wout = (const float*)d_in[2];   // [1024,1024]
  float* out = (float*)d_out;                  // [4,4096,1024] fp32

  char* ws = (char*)d_ws;
  size_t off = 0;
  auto alloc = [&](size_t bytes) -> void* {
    void* p = ws + off;
    off += (bytes + 255) & ~(size_t)255;
    return p;
  };
  unsigned short* xbf    = (unsigned short*)alloc((size_t)16384 * 1024 * 2);  // 33.5 MB
  unsigned short* wqkvbf = (unsigned short*)alloc((size_t)3072 * 1024 * 2);   //  6.3 MB
  unsigned short* woutbf = (unsigned short*)alloc((size_t)1024 * 1024 * 2);   //  2.1 MB
  unsigned short* big    = (unsigned short*)alloc((size_t)16384 * 2048 * 2);  // 67.1 MB (k|v, later q+att)
  float* kvp = (float*)alloc((size_t)SEG * 64 * 4096 * 4);                    // 16.8 MB
  float* ksp = (float*)alloc((size_t)SEG * 64 * 64 * 4);
  unsigned short* kvb = (unsigned short*)alloc((size_t)64 * 80 * 64 * 2);     // 0.66 MB
  unsigned short* qbuf = big;                          // reuse after kv_partial consumed k,v
  unsigned short* att  = big + (size_t)16384 * 1024;   // second half of big

  cast_f32_bf16<<<2048, 256, 0, stream>>>(x, xbf, 16384 * 1024 / 4);
  cast_f32_bf16<<<1024, 256, 0, stream>>>(wqkv, wqkvbf, 3072 * 1024 / 4);
  cast_f32_bf16<<<512, 256, 0, stream>>>(wout, woutbf, 1024 * 1024 / 4);

  // GEMM1a: [k|v] = x @ w_qkv[1024:3072].T ; fm on k cols (<1024)
  gemm256<unsigned short><<<dim3(2048 / 256, 16384 / 256), 512, 0, stream>>>(
      xbf, wqkvbf + (size_t)1024 * 1024, big, 16384, 2048, 1024, 2048, 1024);

  kv_partial<<<64 * SEG, 256, 0, stream>>>(big, kvp, ksp);
  kv_reduce_bf<<<1280, 256, 0, stream>>>(kvp, ksp, kvb);

  // GEMM1b: q = fm(x @ w_qkv[0:1024].T)  (overwrites dead k/v region)
  gemm256<unsigned short><<<dim3(1024 / 256, 16384 / 256), 512, 0, stream>>>(
      xbf, wqkvbf, qbuf, 16384, 1024, 1024, 1024, 1024);

  attn_mfma<<<64 * 16, 256, 0, stream>>>(qbuf, kvb, att);

  // GEMM2: out = att @ w_out.T (fp32 out, no fm)
  gemm256<float><<<dim3(1024 / 256, 16384 / 256), 512, 0, stream>>>(
      att, woutbf, out, 16384, 1024, 1024, 1024, 0);
}

// Round 5
// 258.058 us; speedup vs baseline: 1.7630x; 1.0389x over previous
//
#include <hip/hip_runtime.h>
#include <hip/hip_bf16.h>
#include <stdint.h>

typedef __attribute__((ext_vector_type(8))) short short8;
typedef __attribute__((ext_vector_type(4))) float f32x4;
typedef __attribute__((ext_vector_type(4))) unsigned short ushort4_t;

#define SEG 16

__device__ __forceinline__ float bf2f(unsigned short u) {
  unsigned int x = ((unsigned int)u) << 16;
  return __uint_as_float(x);
}
__device__ __forceinline__ unsigned short f2bf(float f) {
  unsigned int u = __float_as_uint(f);
  u += 0x7fffu + ((u >> 16) & 1u);
  return (unsigned short)(u >> 16);
}

// async global->LDS, 16B per lane, dest = wave-uniform base + lane*16
__device__ __forceinline__ void gload16(const unsigned short* g, unsigned short* l) {
  __builtin_amdgcn_global_load_lds(
      (const __attribute__((address_space(1))) void*)g,
      (__attribute__((address_space(3))) void*)l, 16, 0, 0);
}

// ---------------- cast fp32 -> bf16 (vectorized) ----------------
__global__ void cast_f32_bf16(const float* __restrict__ in,
                              unsigned short* __restrict__ out, int n4) {
  const int stride = gridDim.x * blockDim.x;
  for (int i = blockIdx.x * blockDim.x + threadIdx.x; i < n4; i += stride) {
    const float4 v = ((const float4*)in)[i];
    ushort4_t o;
    o[0] = f2bf(v.x); o[1] = f2bf(v.y); o[2] = f2bf(v.z); o[3] = f2bf(v.w);
    ((ushort4_t*)out)[i] = o;
  }
}

// ============ GEMM 256x256, BK=64, 8-phase interleave (T3+T4+T5) ============
// C[M,N] = A[M,K] * B[N,K]^T. 512 thr = 8 waves (2M x 4N), wave out 128x64.
// LDS 128KB: 2 buffers x (A[256][64] + B[256][64]). Even K-tile -> buf0.
// Chunk swizzle: LDS[row][c3] = G[row][c3 ^ (row&7)] (c3 = 8-elem chunk) so
// fragment ds_read_b128s spread across all 32 banks (128B rows alias mod 32
// words otherwise).
// Per iteration (2 K-tiles t0,t0+1), 8 phases; quadrant order per tile:
// (mh,nh) = (0,0),(0,1),(1,0),(1,1). Region safety (stage only after ALL
// reads of old content are barrier-separated):
//   buf0.A read q0(mh0),q2(mh1) -> free q3 -> staged q4,q5 (A of t0+2)
//   buf0.B read q0,q1           -> free q2 -> staged q2,q3 (B of t0+2)
//   buf1.A read q4,q6           -> free q7 -> staged next-iter q0,q1 (A of t0+3)
//   buf1.B read q4,q5           -> free q6 -> staged q6,q7 (B of t0+3)
// vmcnt(4) (= keep last 2 stages) before end-barrier of q3 and q7 only:
//   q3: drains prev{q6,q7}=B(t0+1) and q0,q1=A(t0+1)  -> buf1 ready for q4
//   q7: drains q2..q5 = B,A of t0+2                   -> buf0 ready for next q0
// Loads thus stay in flight across 3-4 phase barriers; never drained to 0.
#define MIDBAR() do { __builtin_amdgcn_sched_barrier(0); __builtin_amdgcn_s_barrier(); } while (0)
#define ENDBAR() do { __builtin_amdgcn_s_barrier(); __builtin_amdgcn_sched_barrier(0); } while (0)
#define ENDBARV() do { asm volatile("s_waitcnt vmcnt(4)" ::: "memory"); \
                       __builtin_amdgcn_s_barrier(); __builtin_amdgcn_sched_barrier(0); } while (0)

template <typename OutT>
__global__ __launch_bounds__(512, 2) void gemm8p(
    const unsigned short* __restrict__ A, const unsigned short* __restrict__ Bm,
    OutT* __restrict__ C, int M, int N, int K, int ldc, int fm_cols) {
  __shared__ unsigned short lds[65536];  // 128KB
  unsigned short* A0 = lds;              // tile t0   A  [256][64]
  unsigned short* B0 = lds + 16384;      // tile t0   B
  unsigned short* A1 = lds + 32768;      // tile t0+1 A
  unsigned short* B1 = lds + 49152;      // tile t0+1 B
  const int tid = threadIdx.x;
  const int lane = tid & 63;
  const int w = tid >> 6;
  const int wr = w >> 2, wc = w & 3;     // 2x4 wave grid; wave out = 128x64
  // XCD-aware bijective swizzle (nwg % 8 == 0 for all our grids)
  const int gx = gridDim.x;
  const int nwg = gx * gridDim.y;
  const int hwid = blockIdx.y * gx + blockIdx.x;
  const int cpx = nwg >> 3;
  const int L = (hwid & 7) * cpx + (hwid >> 3);
  const int bx = L % gx, by = L / gx;
  const size_t arow0 = (size_t)by * 256;
  const size_t bcol0 = (size_t)bx * 256;
  const int nt = K >> 6;                 // K-tiles (BK=64); K%128==0 assumed
  const int nit = nt >> 1;

  // staging: per gload16, lane l covers row rb+(l>>3), chunk (l&7);
  // source chunk pre-swizzled: (l&7)^(l>>3)  (== c3 ^ (row&7), rb%8==0)
  const int sc8 = ((lane & 7) ^ (lane >> 3)) << 3;
  const unsigned short* Abase = A + (arow0 + (lane >> 3)) * K + sc8;
  const unsigned short* Bbase = Bm + (bcol0 + (lane >> 3)) * K + sc8;

  auto stage = [&](int kt, const unsigned short* mb, unsigned short* region, int half) {
    const int ktw = (kt >= nt) ? kt - nt : kt;  // wrap: harmless dummy restage
    const int rb = half * 128 + w * 16;
    const unsigned short* s = mb + (size_t)rb * K + ktw * 64;
    gload16(s, region + rb * 64);
    gload16(s + (size_t)8 * K, region + (rb + 8) * 64);
  };

  short8 af[4][2];   // current mh's 4 m-frags x 2 k-steps
  short8 bfv[4][2];  // all 4 n-frags x 2 k-steps
  f32x4 acc[8][4] = {};
  const int fr = lane & 15;
  const int kc = lane >> 4;  // k-octet within 32-half

  auto readA = [&](const unsigned short* bufA, int mh) {
#pragma unroll
    for (int mm = 0; mm < 4; ++mm) {
      const int r = wr * 128 + (mh * 4 + mm) * 16 + fr;
#pragma unroll
      for (int ks = 0; ks < 2; ++ks)
        af[mm][ks] = *(const short8*)&bufA[r * 64 + (((ks * 4 + kc) ^ (fr & 7)) << 3)];
    }
  };
  auto readB = [&](const unsigned short* bufB, int nh) {
#pragma unroll
    for (int nn = 0; nn < 2; ++nn) {
      const int n = nh * 2 + nn;
      const int r = wc * 64 + n * 16 + fr;
#pragma unroll
      for (int ks = 0; ks < 2; ++ks)
        bfv[n][ks] = *(const short8*)&bufB[16384 * 0 + r * 64 + (((ks * 4 + kc) ^ (fr & 7)) << 3)];
    }
  };
  auto quad = [&](int mh, int nh) {
    __builtin_amdgcn_s_setprio(1);
#pragma unroll
    for (int mm = 0; mm < 4; ++mm)
#pragma unroll
      for (int nn = 0; nn < 2; ++nn) {
        f32x4& a = acc[mh * 4 + mm][nh * 2 + nn];
        a = __builtin_amdgcn_mfma_f32_16x16x32_bf16(af[mm][0], bfv[nh * 2 + nn][0], a, 0, 0, 0);
        a = __builtin_amdgcn_mfma_f32_16x16x32_bf16(af[mm][1], bfv[nh * 2 + nn][1], a, 0, 0, 0);
      }
    __builtin_amdgcn_s_setprio(0);
  };

  // prologue: tile0 full + tile1 B; drain; barrier
  stage(0, Abase, A0, 0); stage(0, Abase, A0, 1);
  stage(0, Bbase, B0, 0); stage(0, Bbase, B0, 1);
  stage(1, Bbase, B1, 0); stage(1, Bbase, B1, 1);
  asm volatile("s_waitcnt vmcnt(0)" ::: "memory");
  __builtin_amdgcn_s_barrier();
  __builtin_amdgcn_sched_barrier(0);

  for (int i2 = 0; i2 < nit; ++i2) {
    const int t0 = i2 * 2;
    // ---- K-tile t0 (buf0) ----
    readA(A0, 0); readB(B0, 0);
    stage(t0 + 1, Abase, A1, 0);
    MIDBAR(); quad(0, 0); ENDBAR();          // q0

    readB(B0, 1);
    stage(t0 + 1, Abase, A1, 1);
    MIDBAR(); quad(0, 1); ENDBAR();          // q1

    readA(A0, 1);
    stage(t0 + 2, Bbase, B0, 0);
    MIDBAR(); quad(1, 0); ENDBAR();          // q2

    stage(t0 + 2, Bbase, B0, 1);
    MIDBAR(); quad(1, 1); ENDBARV();         // q3: drains A(t0+1),B(t0+1)
    // ---- K-tile t0+1 (buf1) ----
    readA(A1, 0); readB(B1, 0);
    stage(t0 + 2, Abase, A0, 0);
    MIDBAR(); quad(0, 0); ENDBAR();          // q4

    readB(B1, 1);
    stage(t0 + 2, Abase, A0, 1);
    MIDBAR(); quad(0, 1); ENDBAR();          // q5

    readA(A1, 1);
    stage(t0 + 3, Bbase, B1, 0);
    MIDBAR(); quad(1, 0); ENDBAR();          // q6

    stage(t0 + 3, Bbase, B1, 1);
    MIDBAR(); quad(1, 1); ENDBARV();         // q7: drains A(t0+2),B(t0+2)
  }

  // epilogue: C/D layout col=lane&15, row=(lane>>4)*4+j  [verified m89/m91]
  const int qq = lane >> 4;
#pragma unroll
  for (int m = 0; m < 8; ++m) {
#pragma unroll
    for (int n = 0; n < 4; ++n) {
      const int col = (int)bcol0 + wc * 64 + n * 16 + fr;
      const bool dofm = col < fm_cols;
#pragma unroll
      for (int j = 0; j < 4; ++j) {
        const int row = (int)arow0 + wr * 128 + m * 16 + qq * 4 + j;
        float x = acc[m][n][j];
        if (dofm) x = (x > 0.f) ? x + 1.f : __expf(x);
        if constexpr (sizeof(OutT) == 2) {
          C[(size_t)row * ldc + col] = (OutT)f2bf(x);
        } else {
          C[(size_t)row * ldc + col] = x;
        }
      }
    }
  }
}

// ---------------- kv state partials: kv[bh,d,e] = sum_n k[n,d]*v[n,e] ----------------
// kvmat: [16384 rows][2048]: cols 0..1023 = fm(k), 1024..2047 = v
__global__ __launch_bounds__(256) void kv_partial(
    const unsigned short* __restrict__ kvmat, float* __restrict__ kvp,
    float* __restrict__ ksp) {
  const int blk = blockIdx.x;      // 64*SEG
  const int bh = blk >> 4;
  const int seg = blk & (SEG - 1);
  const int b = bh >> 4, h = bh & 15;
  const int rows = 4096 / SEG;     // 256
  const size_t row0 = (size_t)b * 4096 + (size_t)seg * rows;
  const unsigned short* kb = kvmat + row0 * 2048 + h * 64;
  const unsigned short* vb = kvmat + row0 * 2048 + 1024 + h * 64;
  __shared__ float kl[32][64];
  __shared__ float vl[32][64];
  const int tid = threadIdx.x;
  const int d0 = (tid >> 4) * 4, e0 = (tid & 15) * 4;
  const int lr = tid >> 3, lc = (tid & 7) * 8;
  float accm[4][4] = {};
  float ksacc[4] = {0.f, 0.f, 0.f, 0.f};

  for (int c = 0; c < rows; c += 32) {
    __syncthreads();
    {
      const short8 k8 = *(const short8*)(kb + (size_t)(c + lr) * 2048 + lc);
      const short8 v8 = *(const short8*)(vb + (size_t)(c + lr) * 2048 + lc);
#pragma unroll
      for (int j = 0; j < 8; ++j) {
        kl[lr][lc + j] = bf2f((unsigned short)k8[j]);
        vl[lr][lc + j] = bf2f((unsigned short)v8[j]);
      }
    }
    __syncthreads();
#pragma unroll
    for (int r = 0; r < 32; ++r) {
      const f32x4 kd = *(const f32x4*)&kl[r][d0];
      const f32x4 ve = *(const f32x4*)&vl[r][e0];
#pragma unroll
      for (int i = 0; i < 4; ++i) {
        ksacc[i] += kd[i];
#pragma unroll
        for (int j = 0; j < 4; ++j) accm[i][j] += kd[i] * ve[j];
      }
    }
  }
  float* kvout = kvp + ((size_t)seg * 64 + bh) * 4096;
#pragma unroll
  for (int i = 0; i < 4; ++i) {
    f32x4 o = {accm[i][0], accm[i][1], accm[i][2], accm[i][3]};
    *(f32x4*)&kvout[(d0 + i) * 64 + e0] = o;
  }
  if ((tid & 15) == 0) {
#pragma unroll
    for (int i = 0; i < 4; ++i)
      ksp[((size_t)seg * 64 + bh) * 64 + d0 + i] = ksacc[i];
  }
}

// reduce partials -> kvb[bh][80][64] bf16: rows e<64 = kv^T, row 64 = ksum, 65..79 = 0
__global__ void kv_reduce_bf(const float* __restrict__ kvp, const float* __restrict__ ksp,
                             unsigned short* __restrict__ kvb) {
  const int idx = blockIdx.x * 256 + threadIdx.x;  // 64*80*64
  if (idx >= 64 * 80 * 64) return;
  const int bh = idx / 5120, r = idx % 5120, e = r >> 6, d = r & 63;
  float s = 0.f;
  if (e < 64) {
    for (int g = 0; g < SEG; ++g) s += kvp[((size_t)g * 64 + bh) * 4096 + d * 64 + e];
  } else if (e == 64) {
    for (int g = 0; g < SEG; ++g) s += ksp[((size_t)g * 64 + bh) * 64 + d];
  }
  kvb[idx] = f2bf(s);
}

// ---------------- attn via MFMA: att[row, h*64+e] = (q.kv)/(q.ksum + 1e-6) ----------------
__global__ __launch_bounds__(256) void attn_mfma(
    const unsigned short* __restrict__ q,    // [16384][1024] bf16 (fm applied)
    const unsigned short* __restrict__ kvb,  // [64][80][64] bf16
    unsigned short* __restrict__ att) {      // [16384][1024] bf16
  const int bh = blockIdx.x >> 4;
  const int rt = blockIdx.x & 15;
  const int b = bh >> 4, h = bh & 15;
  __shared__ unsigned short As[2 * 256 * 32];  // [ks][row][32]  32KB
  __shared__ unsigned short Bs[2 * 80 * 32];   // [ks][e][32]    10KB
  const int tid = threadIdx.x, lane = tid & 63, wave = tid >> 6;
  const int l4 = lane >> 2;
  const int c8 = (lane & 3) * 8;
  const size_t qrow0 = (size_t)b * 4096 + (size_t)rt * 256;
  const unsigned short* Ab = q + (qrow0 + wave * 64 + l4) * 1024 + h * 64 + c8;
  unsigned short* AsW = As;
#pragma unroll
  for (int ks = 0; ks < 2; ++ks)
#pragma unroll
    for (int i = 0; i < 4; ++i)
      gload16(Ab + (size_t)i * 16 * 1024 + ks * 32,
              AsW + ks * 8192 + wave * 2048 + i * 512);
  for (int c = tid; c < 640; c += 256) {
    const int m0 = c * 8, ks = m0 / 2560, rr = m0 % 2560, e = rr / 32, dk = rr % 32;
    *(short8*)&Bs[m0] = *(const short8*)&kvb[(size_t)bh * 5120 + e * 64 + ks * 32 + dk];
  }
  __syncthreads();

  const int fr = lane & 15, ko = (lane >> 4) * 8;
  short8 af[4][2], bfv[5][2];
#pragma unroll
  for (int m = 0; m < 4; ++m)
#pragma unroll
    for (int ks = 0; ks < 2; ++ks)
      af[m][ks] = *(const short8*)&As[ks * 8192 + (wave * 64 + m * 16 + fr) * 32 + ko];
#pragma unroll
  for (int n = 0; n < 5; ++n)
#pragma unroll
    for (int ks = 0; ks < 2; ++ks)
      bfv[n][ks] = *(const short8*)&Bs[ks * 2560 + (n * 16 + fr) * 32 + ko];
  f32x4 acc[4][5] = {};
#pragma unroll
  for (int m = 0; m < 4; ++m)
#pragma unroll
    for (int n = 0; n < 5; ++n) {
      acc[m][n] = __builtin_amdgcn_mfma_f32_16x16x32_bf16(af[m][0], bfv[n][0], acc[m][n], 0, 0, 0);
      acc[m][n] = __builtin_amdgcn_mfma_f32_16x16x32_bf16(af[m][1], bfv[n][1], acc[m][n], 0, 0, 0);
    }

  const int qq = lane >> 4;
#pragma unroll
  for (int m = 0; m < 4; ++m) {
    f32x4 rnv;
#pragma unroll
    for (int j = 0; j < 4; ++j) {
      const float nv = __shfl(acc[m][4][j], lane & 48);
      rnv[j] = 1.f / (nv + 1e-6f);
    }
    const size_t row = qrow0 + wave * 64 + m * 16 + qq * 4;
#pragma unroll
    for (int n = 0; n < 4; ++n)
#pragma unroll
      for (int j = 0; j < 4; ++j)
        att[(row + j) * 1024 + h * 64 + n * 16 + fr] = f2bf(acc[m][n][j] * rnv[j]);
  }
}

extern "C" void kernel_launch(void* const* d_in, const int* in_sizes, int n_in,
                              void* d_out, int out_size, void* d_ws, size_t ws_size,
                              hipStream_t stream) {
  const float* x = (const float*)d_in[0];      // [4,4096,1024]
  const float* wqkv = (const float*)d_in[1];   // [3072,1024]
  const float* wout = (const float*)d_in[2];   // [1024,1024]
  float* out = (float*)d_out;                  // [4,4096,1024] fp32

  char* ws = (char*)d_ws;
  size_t off = 0;
  auto alloc = [&](size_t bytes) -> void* {
    void* p = ws + off;
    off += (bytes + 255) & ~(size_t)255;
    return p;
  };
  unsigned short* xbf    = (unsigned short*)alloc((size_t)16384 * 1024 * 2);  // 33.5 MB
  unsigned short* wqkvbf = (unsigned short*)alloc((size_t)3072 * 1024 * 2);   //  6.3 MB
  unsigned short* woutbf = (unsigned short*)alloc((size_t)1024 * 1024 * 2);   //  2.1 MB
  unsigned short* big    = (unsigned short*)alloc((size_t)16384 * 2048 * 2);  // 67.1 MB (k|v, later q+att)
  float* kvp = (float*)alloc((size_t)SEG * 64 * 4096 * 4);                    // 16.8 MB
  float* ksp = (float*)alloc((size_t)SEG * 64 * 64 * 4);
  unsigned short* kvb = (unsigned short*)alloc((size_t)64 * 80 * 64 * 2);     // 0.66 MB
  unsigned short* qbuf = big;                          // reuse after kv_partial consumed k,v
  unsigned short* att  = big + (size_t)16384 * 1024;   // second half of big

  cast_f32_bf16<<<2048, 256, 0, stream>>>(x, xbf, 16384 * 1024 / 4);
  cast_f32_bf16<<<1024, 256, 0, stream>>>(wqkv, wqkvbf, 3072 * 1024 / 4);
  cast_f32_bf16<<<512, 256, 0, stream>>>(wout, woutbf, 1024 * 1024 / 4);

  // GEMM1a: [k|v] = x @ w_qkv[1024:3072].T ; fm on k cols (<1024)
  gemm8p<unsigned short><<<dim3(2048 / 256, 16384 / 256), 512, 0, stream>>>(
      xbf, wqkvbf + (size_t)1024 * 1024, big, 16384, 2048, 1024, 2048, 1024);

  kv_partial<<<64 * SEG, 256, 0, stream>>>(big, kvp, ksp);
  kv_reduce_bf<<<1280, 256, 0, stream>>>(kvp, ksp, kvb);

  // GEMM1b: q = fm(x @ w_qkv[0:1024].T)  (overwrites dead k/v region)
  gemm8p<unsigned short><<<dim3(1024 / 256, 16384 / 256), 512, 0, stream>>>(
      xbf, wqkvbf, qbuf, 16384, 1024, 1024, 1024, 1024);

  attn_mfma<<<64 * 16, 256, 0, stream>>>(qbuf, kvb, att);

  // GEMM2: out = att @ w_out.T (fp32 out, no fm)
  gemm8p<float><<<dim3(1024 / 256, 16384 / 256), 512, 0, stream>>>(
      att, woutbf, out, 16384, 1024, 1024, 1024, 0);
}